// Round 2
// baseline (388.819 us; speedup 1.0000x reference)
//
#include <hip/hip_runtime.h>
#include <stdint.h>

// ---------------------------------------------------------------------------
// Fused LocalBranch: ResNetMLP (5x GEMM+LN) + per-graph distance softmax pool.
// One workgroup (512 thr = 8 waves) per graph; activations live in LDS (bf16),
// residual stream in fp32 registers, weights pre-cast to bf16 W^T in d_ws.
// R2: amdgpu_waves_per_eu(2,2) -> 256-VGPR budget, kills the 139 MB scratch
//     spill seen in R1 counters; tiled-transpose weight prep.
// ---------------------------------------------------------------------------

typedef __attribute__((ext_vector_type(8))) short bf16x8;   // 8 bf16 = 4 VGPRs
typedef __attribute__((ext_vector_type(4))) float f32x4;

#define XB_STRIDE 264            // 256 + 8 bf16 pad (16B-aligned rows, 2-way bank alias = free)
#define BB_STRIDE 72             // 64 + 8 bf16 pad per B-chunk row
#define BB_BUFSZ  (256 * 72)     // elems per B buffer
#define LDS_BB    67584          // byte offsets into dynamic LDS
#define LDS_PAR   141312
#define LDS_STATS 155136
#define LDS_STATQ 157184
#define LDS_SQV   159232
#define LDS_SM    159744
#define LDS_SMW   160256
#define LDS_TOTAL 160768

__device__ __forceinline__ unsigned short f2bf(float f) {
  unsigned int u = __builtin_bit_cast(unsigned int, f);
  u += 0x7fffu + ((u >> 16) & 1u);           // RNE
  return (unsigned short)(u >> 16);
}
__device__ __forceinline__ float bf2f(unsigned short h) {
  unsigned int u = ((unsigned int)h) << 16;
  return __builtin_bit_cast(float, u);
}
__device__ __forceinline__ f32x4 zero4() {
  f32x4 v; v.x = 0.f; v.y = 0.f; v.z = 0.f; v.w = 0.f; return v;
}

// ---------------------------------------------------------------------------
// Weight prep via 64x64 LDS tile transpose: fp32 [K][N] -> bf16 W^T [N][K].
// ws layout (bf16 elems): Wt_in [256][64] @0 ; Wt_b[k] [256][256] @16384+k*65536 ;
//                         Wt_out [128][256] @212992  (total 245760 elems)
// Tiles: 0..3 Win (K=64,N=256); 4..51 Wb (3 blocks x 4x4); 52..59 Wout (4x2).
// ---------------------------------------------------------------------------
__global__ void prep_weights(const float* __restrict__ Win, const float* __restrict__ Wb,
                             const float* __restrict__ Wout, unsigned short* __restrict__ ws) {
  __shared__ float tile[64][65];
  const int t = blockIdx.x;
  const float* src; unsigned short* dst; int nsrc, kl, k0, n0;
  if (t < 4) {
    src = Win; dst = ws; nsrc = 256; kl = 64; k0 = 0; n0 = t * 64;
  } else if (t < 52) {
    int i = t - 4, blk = i >> 4, r = i & 15;
    src = Wb + blk * 65536; dst = ws + 16384 + blk * 65536;
    nsrc = 256; kl = 256; k0 = (r >> 2) * 64; n0 = (r & 3) * 64;
  } else {
    int i = t - 52;
    src = Wout; dst = ws + 212992;
    nsrc = 128; kl = 256; k0 = (i >> 1) * 64; n0 = (i & 1) * 64;
  }
  const int tid = threadIdx.x;
#pragma unroll
  for (int it = 0; it < 4; ++it) {           // coalesced float4 reads
    int r = it * 16 + (tid >> 4);
    int c4 = (tid & 15) * 4;
    float4 v = *reinterpret_cast<const float4*>(src + (size_t)(k0 + r) * nsrc + n0 + c4);
    tile[c4 + 0][r] = v.x; tile[c4 + 1][r] = v.y;
    tile[c4 + 2][r] = v.z; tile[c4 + 3][r] = v.w;
  }
  __syncthreads();
#pragma unroll
  for (int it = 0; it < 4; ++it) {           // coalesced ushort4 writes
    int n = it * 16 + (tid >> 4);
    int c = (tid & 15) * 4;
    ushort4 o;
    o.x = f2bf(tile[n][c + 0]); o.y = f2bf(tile[n][c + 1]);
    o.z = f2bf(tile[n][c + 2]); o.w = f2bf(tile[n][c + 3]);
    *reinterpret_cast<ushort4*>(dst + (size_t)(n0 + n) * kl + k0 + c) = o;
  }
}

// ---------------------------------------------------------------------------
// One GEMM(+bias+LN+act+residual) layer. Wave tile = 64 rows x (NT*16) cols.
// KL = K of layer; NT = n-subtiles per wave (4 -> N=256, 2 -> N=128).
// MODE: 0 = stem (x=relu(ln)), 1 = residual (x+=relu(ln)), 2 = head (z=ln).
// B double-buffered in LDS, K-chunks of 64, fetch-next-before-compute.
// ---------------------------------------------------------------------------
template <int KL, int NT, int MODE>
__device__ __forceinline__ void layer_gemm(char* smem, const unsigned short* __restrict__ Wt,
                                           int tid, int wave, int lane,
                                           int parB, int parG, int parBe,
                                           f32x4 (&xres)[4][4], int par0) {
  const int mr = wave >> 2;          // 0..1 : row-block of wave
  const int nc = wave & 3;           // 0..3 : col-block of wave
  const int q = lane >> 4;
  const int l16 = lane & 15;
  unsigned short* Xb = (unsigned short*)smem;
  unsigned short* BbAll = (unsigned short*)(smem + LDS_BB);
  float* par = (float*)(smem + LDS_PAR);
  float* statS = (float*)(smem + LDS_STATS);
  float* statQ = (float*)(smem + LDS_STATQ);
  constexpr int C = KL / 64;
  constexpr int NLOAD = NT;          // (NT*64 cols total)*8 units / 512 thr
  constexpr int NCOLS = NT * 64;
  const int colbase = nc * (NT * 16);

  f32x4 acc[4][NT];
#pragma unroll
  for (int mt = 0; mt < 4; ++mt)
#pragma unroll
    for (int nt = 0; nt < NT; ++nt) acc[mt][nt] = zero4();

  uint4 rr[NLOAD];
#pragma unroll
  for (int i = 0; i < NLOAD; ++i) {  // fetch chunk 0
    int u = tid + i * 512;
    rr[i] = *reinterpret_cast<const uint4*>(Wt + (u >> 3) * KL + (u & 7) * 8);
  }
  for (int c = 0; c < C; ++c) {
    unsigned short* Bb = BbAll + ((par0 + c) & 1) * BB_BUFSZ;
#pragma unroll
    for (int i = 0; i < NLOAD; ++i) {
      int u = tid + i * 512;
      *reinterpret_cast<uint4*>(Bb + (u >> 3) * BB_STRIDE + (u & 7) * 8) = rr[i];
    }
    __syncthreads();                 // chunk c staged (also covers X written last layer)
    if (c + 1 < C) {
#pragma unroll
      for (int i = 0; i < NLOAD; ++i) {
        int u = tid + i * 512;
        rr[i] = *reinterpret_cast<const uint4*>(Wt + (u >> 3) * KL + (c + 1) * 64 + (u & 7) * 8);
      }
    }
#pragma unroll
    for (int ks = 0; ks < 2; ++ks) {
      const int kk = c * 64 + ks * 32 + q * 8;
      bf16x8 a[4], b[NT];
#pragma unroll
      for (int mt = 0; mt < 4; ++mt)
        a[mt] = *reinterpret_cast<const bf16x8*>(Xb + (64 * mr + 16 * mt + l16) * XB_STRIDE + kk);
#pragma unroll
      for (int nt = 0; nt < NT; ++nt)
        b[nt] = *reinterpret_cast<const bf16x8*>(Bb + (colbase + 16 * nt + l16) * BB_STRIDE + ks * 32 + q * 8);
#pragma unroll
      for (int mt = 0; mt < 4; ++mt)
#pragma unroll
        for (int nt = 0; nt < NT; ++nt)
          acc[mt][nt] = __builtin_amdgcn_mfma_f32_16x16x32_bf16(a[mt], b[nt], acc[mt][nt], 0, 0, 0);
    }
  }
  // ---- epilogue: bias, cross-wave LN stats, normalize, act, residual, store
#pragma unroll
  for (int mt = 0; mt < 4; ++mt) {
#pragma unroll
    for (int nt = 0; nt < NT; ++nt) {
      float bc = par[parB + colbase + 16 * nt + l16];
      acc[mt][nt].x += bc; acc[mt][nt].y += bc; acc[mt][nt].z += bc; acc[mt][nt].w += bc;
    }
    f32x4 s1 = acc[mt][0];
    f32x4 s2 = acc[mt][0] * acc[mt][0];
#pragma unroll
    for (int nt = 1; nt < NT; ++nt) { s1 += acc[mt][nt]; s2 += acc[mt][nt] * acc[mt][nt]; }
#pragma unroll
    for (int d = 1; d < 16; d <<= 1) {
#pragma unroll
      for (int r = 0; r < 4; ++r) {
        float t1 = s1[r]; t1 += __shfl_xor(t1, d); s1[r] = t1;
        float t2 = s2[r]; t2 += __shfl_xor(t2, d); s2[r] = t2;
      }
    }
    if (l16 == 0) {
#pragma unroll
      for (int r = 0; r < 4; ++r) {
        int row = 64 * mr + 16 * mt + q * 4 + r;
        statS[row * 4 + nc] = s1[r];
        statQ[row * 4 + nc] = s2[r];
      }
    }
  }
  __syncthreads();                   // stats published (also fences all B reads)
#pragma unroll
  for (int mt = 0; mt < 4; ++mt) {
#pragma unroll
    for (int r = 0; r < 4; ++r) {
      int row = 64 * mr + 16 * mt + q * 4 + r;
      float S1 = statS[row * 4 + 0] + statS[row * 4 + 1] + statS[row * 4 + 2] + statS[row * 4 + 3];
      float S2 = statQ[row * 4 + 0] + statQ[row * 4 + 1] + statQ[row * 4 + 2] + statQ[row * 4 + 3];
      float mu = S1 * (1.0f / NCOLS);
      float var = S2 * (1.0f / NCOLS) - mu * mu;
      float rstd = rsqrtf(var + 1e-5f);
#pragma unroll
      for (int nt = 0; nt < NT; ++nt) {
        int col = colbase + 16 * nt + l16;
        float y = (acc[mt][nt][r] - mu) * rstd * par[parG + col] + par[parBe + col];
        float xv;
        if constexpr (MODE == 0) { xv = fmaxf(y, 0.f); xres[mt][nt][r] = xv; }
        else if constexpr (MODE == 1) { xv = xres[mt][nt][r] + fmaxf(y, 0.f); xres[mt][nt][r] = xv; }
        else { xv = y; }
        Xb[row * XB_STRIDE + col] = f2bf(xv);
      }
    }
  }
}

// ---------------------------------------------------------------------------
// waves_per_eu(2,2): pin allocator to 2 waves/EU (the occupancy we get anyway
// with one 512-thr block/CU) -> 256-VGPR budget -> no scratch spill of xres.
// ---------------------------------------------------------------------------
__global__ __attribute__((amdgpu_flat_work_group_size(512, 512), amdgpu_waves_per_eu(2, 2)))
void fused_main(
    const float* __restrict__ H, const unsigned short* __restrict__ ws,
    const float* __restrict__ b_in, const float* __restrict__ g_in, const float* __restrict__ beta_in,
    const float* __restrict__ bb, const float* __restrict__ gb, const float* __restrict__ betab,
    const float* __restrict__ b_out, const float* __restrict__ g_out, const float* __restrict__ beta_out,
    float* __restrict__ out) {
  extern __shared__ char smem[];
  const int tid = threadIdx.x;
  const int gidx = blockIdx.x;
  const int wave = tid >> 6;
  const int lane = tid & 63;
  const int q = lane >> 4;
  const int l16 = lane & 15;
  unsigned short* Xb = (unsigned short*)smem;
  float* par = (float*)(smem + LDS_PAR);
  float* sqv = (float*)(smem + LDS_SQV);
  float* sm  = (float*)(smem + LDS_SM);
  float* smw = (float*)(smem + LDS_SMW);

  // stage LN/bias params -> LDS (visibility covered by first chunk barrier)
  for (int i = tid; i < 3456; i += 512) {
    float v;
    if (i < 256) v = b_in[i];
    else if (i < 512) v = g_in[i - 256];
    else if (i < 768) v = beta_in[i - 512];
    else if (i < 1536) v = bb[i - 768];
    else if (i < 2304) v = gb[i - 1536];
    else if (i < 3072) v = betab[i - 2304];
    else if (i < 3200) v = b_out[i - 3072];
    else if (i < 3328) v = g_out[i - 3200];
    else v = beta_out[i - 3328];
    par[i] = v;
  }
  // stage H tile (128x64) -> Xb as bf16
  {
    int row = tid >> 2, cb0 = (tid & 3) * 16;
    const float4* hp = reinterpret_cast<const float4*>(H + (size_t)(gidx * 128 + row) * 64 + cb0);
#pragma unroll
    for (int v4 = 0; v4 < 4; ++v4) {
      float4 f = hp[v4];
      int cb = cb0 + v4 * 4;
      Xb[row * XB_STRIDE + cb + 0] = f2bf(f.x);
      Xb[row * XB_STRIDE + cb + 1] = f2bf(f.y);
      Xb[row * XB_STRIDE + cb + 2] = f2bf(f.z);
      Xb[row * XB_STRIDE + cb + 3] = f2bf(f.w);
    }
  }

  f32x4 xres[4][4];
  layer_gemm<64, 4, 0>(smem, ws, tid, wave, lane, 0, 256, 512, xres, 0);
  layer_gemm<256, 4, 1>(smem, ws + 16384,          tid, wave, lane,  768, 1536, 2304, xres, 1);
  layer_gemm<256, 4, 1>(smem, ws + 16384 + 65536,  tid, wave, lane, 1024, 1792, 2560, xres, 1);
  layer_gemm<256, 4, 1>(smem, ws + 16384 + 131072, tid, wave, lane, 1280, 2048, 2816, xres, 1);
  layer_gemm<256, 2, 2>(smem, ws + 212992,         tid, wave, lane, 3072, 3200, 3328, xres, 1);
  __syncthreads();                       // Z (bf16, Xb cols 0..127) ready for all waves

  // ---- gram G = Z Z^T : wave owns 16 rows x 128 cols
  f32x4 g2[8];
#pragma unroll
  for (int nt = 0; nt < 8; ++nt) g2[nt] = zero4();
#pragma unroll
  for (int ks = 0; ks < 4; ++ks) {
    int kk = ks * 32 + q * 8;
    bf16x8 a = *reinterpret_cast<const bf16x8*>(Xb + (16 * wave + l16) * XB_STRIDE + kk);
#pragma unroll
    for (int nt = 0; nt < 8; ++nt) {
      bf16x8 bfr = *reinterpret_cast<const bf16x8*>(Xb + (16 * nt + l16) * XB_STRIDE + kk);
      g2[nt] = __builtin_amdgcn_mfma_f32_16x16x32_bf16(a, bfr, g2[nt], 0, 0, 0);
    }
  }
  // publish sq_i = G_ii (diag) so that d_ii == sqrt(1e-12) exactly like ref
  if ((l16 >> 2) == q) {
#pragma unroll
    for (int nt = 0; nt < 8; ++nt)
      if (nt == wave) {
#pragma unroll
        for (int r = 0; r < 4; ++r)
          if ((l16 & 3) == r) sqv[16 * wave + l16] = g2[nt][r];
      }
  }
  __syncthreads();
  // ---- distances and s_i = mean_j d_ij
  float sqi[4];
#pragma unroll
  for (int r = 0; r < 4; ++r) sqi[r] = sqv[16 * wave + q * 4 + r];
  float sp[4] = {0.f, 0.f, 0.f, 0.f};
#pragma unroll
  for (int nt = 0; nt < 8; ++nt) {
    float sqj = sqv[16 * nt + l16];
#pragma unroll
    for (int r = 0; r < 4; ++r) {
      float d2 = sqi[r] + sqj - 2.0f * g2[nt][r];
      sp[r] += sqrtf(fmaxf(d2, 0.f) + 1e-12f);
    }
  }
#pragma unroll
  for (int d = 1; d < 16; d <<= 1) {
#pragma unroll
    for (int r = 0; r < 4; ++r) { float t = sp[r]; t += __shfl_xor(t, d); sp[r] = t; }
  }
  if (l16 == 0) {
#pragma unroll
    for (int r = 0; r < 4; ++r) sm[16 * wave + q * 4 + r] = sp[r] * (1.0f / 128.0f);
  }
  __syncthreads();
  // ---- softmax(s/TAU) by wave 0 (1/TAU = 4)
  if (wave == 0) {
    float l0 = sm[lane] * 4.0f;
    float l1 = sm[lane + 64] * 4.0f;
    float mx = fmaxf(l0, l1);
#pragma unroll
    for (int d = 1; d < 64; d <<= 1) mx = fmaxf(mx, __shfl_xor(mx, d));
    float e0 = __expf(l0 - mx), e1 = __expf(l1 - mx);
    float ss = e0 + e1;
#pragma unroll
    for (int d = 1; d < 64; d <<= 1) ss += __shfl_xor(ss, d);
    float inv = 1.0f / ss;
    float w0 = e0 * inv, w1 = e1 * inv;
    smw[lane] = w0;
    smw[lane + 64] = w1;
    out[131072 + gidx * 128 + lane] = w0;
    out[131072 + gidx * 128 + 64 + lane] = w1;
  }
  __syncthreads();
  // ---- v_loc = sum_i w_i * Z[i,:] ; wave covers 16 cols, lanes split rows by q
  {
    int c = 16 * wave + l16;
    float acv = 0.f;
#pragma unroll
    for (int i0 = 0; i0 < 32; ++i0) {
      int i = q * 32 + i0;
      acv += smw[i] * bf2f(Xb[i * XB_STRIDE + c]);
    }
    acv += __shfl_xor(acv, 16);
    acv += __shfl_xor(acv, 32);
    if (q == 0) out[gidx * 128 + c] = acv;
  }
}

// ---------------------------------------------------------------------------
extern "C" void kernel_launch(void* const* d_in, const int* in_sizes, int n_in,
                              void* d_out, int out_size, void* d_ws, size_t ws_size,
                              hipStream_t stream) {
  (void)in_sizes; (void)n_in; (void)out_size; (void)ws_size;
  const float* H        = (const float*)d_in[0];
  // d_in[1] = batch_ptr (uniform 128/graph, unused)
  const float* W_in     = (const float*)d_in[2];
  const float* b_in     = (const float*)d_in[3];
  const float* g_in     = (const float*)d_in[4];
  const float* beta_in  = (const float*)d_in[5];
  const float* Wb       = (const float*)d_in[6];
  const float* bb       = (const float*)d_in[7];
  const float* gb       = (const float*)d_in[8];
  const float* betab    = (const float*)d_in[9];
  const float* W_out    = (const float*)d_in[10];
  const float* b_out    = (const float*)d_in[11];
  const float* g_out    = (const float*)d_in[12];
  const float* beta_out = (const float*)d_in[13];
  float* out = (float*)d_out;
  unsigned short* ws = (unsigned short*)d_ws;

  // re-create bf16 transposed weights every call (ws is re-poisoned each launch)
  prep_weights<<<60, 256, 0, stream>>>(W_in, Wb, W_out, ws);

  hipFuncSetAttribute(reinterpret_cast<const void*>(fused_main),
                      hipFuncAttributeMaxDynamicSharedMemorySize, LDS_TOTAL);
  fused_main<<<1024, 512, LDS_TOTAL, stream>>>(H, ws, b_in, g_in, beta_in,
                                               bb, gb, betab, b_out, g_out, beta_out, out);
}

// Round 3
// 321.677 us; speedup vs baseline: 1.2087x; 1.2087x over previous
//
#include <hip/hip_runtime.h>
#include <stdint.h>

// ---------------------------------------------------------------------------
// Fused LocalBranch: ResNetMLP (5x GEMM+LN) + per-graph distance softmax pool.
// One workgroup (512 thr = 8 waves) per graph; activations live in LDS (bf16),
// weights pre-cast to bf16 W^T in d_ws.
// R3: residual stream carried in bf16 via Xb (LDS) instead of fp32 registers.
//     R1/R2 counters showed 141 MB scratch traffic = the 64-reg fp32 xres
//     spilling across layer barriers (arch budget is 128 of the 256 unified).
//     acc(64 AGPR) + frags + addressing now fits: no spill.
// ---------------------------------------------------------------------------

typedef __attribute__((ext_vector_type(8))) short bf16x8;   // 8 bf16 = 4 VGPRs
typedef __attribute__((ext_vector_type(4))) float f32x4;

#define XB_STRIDE 264            // 256 + 8 bf16 pad (16B-aligned rows, 2-way bank alias = free)
#define BB_STRIDE 72             // 64 + 8 bf16 pad per B-chunk row
#define BB_BUFSZ  (256 * 72)     // elems per B buffer
#define LDS_BB    67584          // byte offsets into dynamic LDS
#define LDS_PAR   141312
#define LDS_STATS 155136
#define LDS_STATQ 157184
#define LDS_SQV   159232
#define LDS_SM    159744
#define LDS_SMW   160256
#define LDS_TOTAL 160768

__device__ __forceinline__ unsigned short f2bf(float f) {
  unsigned int u = __builtin_bit_cast(unsigned int, f);
  u += 0x7fffu + ((u >> 16) & 1u);           // RNE
  return (unsigned short)(u >> 16);
}
__device__ __forceinline__ float bf2f(unsigned short h) {
  unsigned int u = ((unsigned int)h) << 16;
  return __builtin_bit_cast(float, u);
}
__device__ __forceinline__ f32x4 zero4() {
  f32x4 v; v.x = 0.f; v.y = 0.f; v.z = 0.f; v.w = 0.f; return v;
}

// ---------------------------------------------------------------------------
// Weight prep via 64x64 LDS tile transpose: fp32 [K][N] -> bf16 W^T [N][K].
// ws layout (bf16 elems): Wt_in [256][64] @0 ; Wt_b[k] [256][256] @16384+k*65536 ;
//                         Wt_out [128][256] @212992  (total 245760 elems)
// Tiles: 0..3 Win (K=64,N=256); 4..51 Wb (3 blocks x 4x4); 52..59 Wout (4x2).
// ---------------------------------------------------------------------------
__global__ void prep_weights(const float* __restrict__ Win, const float* __restrict__ Wb,
                             const float* __restrict__ Wout, unsigned short* __restrict__ ws) {
  __shared__ float tile[64][65];
  const int t = blockIdx.x;
  const float* src; unsigned short* dst; int nsrc, kl, k0, n0;
  if (t < 4) {
    src = Win; dst = ws; nsrc = 256; kl = 64; k0 = 0; n0 = t * 64;
  } else if (t < 52) {
    int i = t - 4, blk = i >> 4, r = i & 15;
    src = Wb + blk * 65536; dst = ws + 16384 + blk * 65536;
    nsrc = 256; kl = 256; k0 = (r >> 2) * 64; n0 = (r & 3) * 64;
  } else {
    int i = t - 52;
    src = Wout; dst = ws + 212992;
    nsrc = 128; kl = 256; k0 = (i >> 1) * 64; n0 = (i & 1) * 64;
  }
  const int tid = threadIdx.x;
#pragma unroll
  for (int it = 0; it < 4; ++it) {           // coalesced float4 reads
    int r = it * 16 + (tid >> 4);
    int c4 = (tid & 15) * 4;
    float4 v = *reinterpret_cast<const float4*>(src + (size_t)(k0 + r) * nsrc + n0 + c4);
    tile[c4 + 0][r] = v.x; tile[c4 + 1][r] = v.y;
    tile[c4 + 2][r] = v.z; tile[c4 + 3][r] = v.w;
  }
  __syncthreads();
#pragma unroll
  for (int it = 0; it < 4; ++it) {           // coalesced ushort4 writes
    int n = it * 16 + (tid >> 4);
    int c = (tid & 15) * 4;
    ushort4 o;
    o.x = f2bf(tile[n][c + 0]); o.y = f2bf(tile[n][c + 1]);
    o.z = f2bf(tile[n][c + 2]); o.w = f2bf(tile[n][c + 3]);
    *reinterpret_cast<ushort4*>(dst + (size_t)(n0 + n) * kl + k0 + c) = o;
  }
}

// ---------------------------------------------------------------------------
// One GEMM(+bias+LN+act+residual) layer. Wave tile = 64 rows x (NT*16) cols.
// KL = K of layer; NT = n-subtiles per wave (4 -> N=256, 2 -> N=128).
// MODE: 0 = stem (x=relu(ln)), 1 = residual (x = Xb + relu(ln), bf16 carry),
//       2 = head (z=ln).
// B double-buffered in LDS, K-chunks of 64, fetch-next-before-compute.
// ---------------------------------------------------------------------------
template <int KL, int NT, int MODE>
__device__ __forceinline__ void layer_gemm(char* smem, const unsigned short* __restrict__ Wt,
                                           int tid, int wave, int lane,
                                           int parB, int parG, int parBe, int par0) {
  const int mr = wave >> 2;          // 0..1 : row-block of wave
  const int nc = wave & 3;           // 0..3 : col-block of wave
  const int q = lane >> 4;
  const int l16 = lane & 15;
  unsigned short* Xb = (unsigned short*)smem;
  unsigned short* BbAll = (unsigned short*)(smem + LDS_BB);
  float* par = (float*)(smem + LDS_PAR);
  float* statS = (float*)(smem + LDS_STATS);
  float* statQ = (float*)(smem + LDS_STATQ);
  constexpr int C = KL / 64;
  constexpr int NLOAD = NT;          // (NT*64 cols total)*8 units / 512 thr
  constexpr int NCOLS = NT * 64;
  const int colbase = nc * (NT * 16);

  f32x4 acc[4][NT];
#pragma unroll
  for (int mt = 0; mt < 4; ++mt)
#pragma unroll
    for (int nt = 0; nt < NT; ++nt) acc[mt][nt] = zero4();

  uint4 rr[NLOAD];
#pragma unroll
  for (int i = 0; i < NLOAD; ++i) {  // fetch chunk 0
    int u = tid + i * 512;
    rr[i] = *reinterpret_cast<const uint4*>(Wt + (u >> 3) * KL + (u & 7) * 8);
  }
  for (int c = 0; c < C; ++c) {
    unsigned short* Bb = BbAll + ((par0 + c) & 1) * BB_BUFSZ;
#pragma unroll
    for (int i = 0; i < NLOAD; ++i) {
      int u = tid + i * 512;
      *reinterpret_cast<uint4*>(Bb + (u >> 3) * BB_STRIDE + (u & 7) * 8) = rr[i];
    }
    __syncthreads();                 // chunk c staged (also covers X written last layer)
    if (c + 1 < C) {
#pragma unroll
      for (int i = 0; i < NLOAD; ++i) {
        int u = tid + i * 512;
        rr[i] = *reinterpret_cast<const uint4*>(Wt + (u >> 3) * KL + (c + 1) * 64 + (u & 7) * 8);
      }
    }
#pragma unroll
    for (int ks = 0; ks < 2; ++ks) {
      const int kk = c * 64 + ks * 32 + q * 8;
      bf16x8 a[4], b[NT];
#pragma unroll
      for (int mt = 0; mt < 4; ++mt)
        a[mt] = *reinterpret_cast<const bf16x8*>(Xb + (64 * mr + 16 * mt + l16) * XB_STRIDE + kk);
#pragma unroll
      for (int nt = 0; nt < NT; ++nt)
        b[nt] = *reinterpret_cast<const bf16x8*>(Bb + (colbase + 16 * nt + l16) * BB_STRIDE + ks * 32 + q * 8);
#pragma unroll
      for (int mt = 0; mt < 4; ++mt)
#pragma unroll
        for (int nt = 0; nt < NT; ++nt)
          acc[mt][nt] = __builtin_amdgcn_mfma_f32_16x16x32_bf16(a[mt], b[nt], acc[mt][nt], 0, 0, 0);
    }
  }
  // ---- epilogue: bias, cross-wave LN stats, normalize, act, residual, store
#pragma unroll
  for (int mt = 0; mt < 4; ++mt) {
#pragma unroll
    for (int nt = 0; nt < NT; ++nt) {
      float bc = par[parB + colbase + 16 * nt + l16];
      acc[mt][nt].x += bc; acc[mt][nt].y += bc; acc[mt][nt].z += bc; acc[mt][nt].w += bc;
    }
    f32x4 s1 = acc[mt][0];
    f32x4 s2 = acc[mt][0] * acc[mt][0];
#pragma unroll
    for (int nt = 1; nt < NT; ++nt) { s1 += acc[mt][nt]; s2 += acc[mt][nt] * acc[mt][nt]; }
#pragma unroll
    for (int d = 1; d < 16; d <<= 1) {
#pragma unroll
      for (int r = 0; r < 4; ++r) {
        float t1 = s1[r]; t1 += __shfl_xor(t1, d); s1[r] = t1;
        float t2 = s2[r]; t2 += __shfl_xor(t2, d); s2[r] = t2;
      }
    }
    if (l16 == 0) {
#pragma unroll
      for (int r = 0; r < 4; ++r) {
        int row = 64 * mr + 16 * mt + q * 4 + r;
        statS[row * 4 + nc] = s1[r];
        statQ[row * 4 + nc] = s2[r];
      }
    }
  }
  __syncthreads();                   // stats published (also fences all B reads)
#pragma unroll
  for (int mt = 0; mt < 4; ++mt) {
#pragma unroll
    for (int r = 0; r < 4; ++r) {
      int row = 64 * mr + 16 * mt + q * 4 + r;
      float S1 = statS[row * 4 + 0] + statS[row * 4 + 1] + statS[row * 4 + 2] + statS[row * 4 + 3];
      float S2 = statQ[row * 4 + 0] + statQ[row * 4 + 1] + statQ[row * 4 + 2] + statQ[row * 4 + 3];
      float mu = S1 * (1.0f / NCOLS);
      float var = S2 * (1.0f / NCOLS) - mu * mu;
      float rstd = rsqrtf(var + 1e-5f);
#pragma unroll
      for (int nt = 0; nt < NT; ++nt) {
        int col = colbase + 16 * nt + l16;
        float y = (acc[mt][nt][r] - mu) * rstd * par[parG + col] + par[parBe + col];
        float xv;
        if constexpr (MODE == 0) { xv = fmaxf(y, 0.f); }
        else if constexpr (MODE == 1) {
          // residual base = this thread's own previous bf16 activation (same
          // (row,col) slot it stored last layer; fenced by the stats barrier)
          xv = bf2f(Xb[row * XB_STRIDE + col]) + fmaxf(y, 0.f);
        } else { xv = y; }
        Xb[row * XB_STRIDE + col] = f2bf(xv);
      }
    }
  }
}

// ---------------------------------------------------------------------------
__global__ __attribute__((amdgpu_flat_work_group_size(512, 512), amdgpu_waves_per_eu(2, 2)))
void fused_main(
    const float* __restrict__ H, const unsigned short* __restrict__ ws,
    const float* __restrict__ b_in, const float* __restrict__ g_in, const float* __restrict__ beta_in,
    const float* __restrict__ bb, const float* __restrict__ gb, const float* __restrict__ betab,
    const float* __restrict__ b_out, const float* __restrict__ g_out, const float* __restrict__ beta_out,
    float* __restrict__ out) {
  extern __shared__ char smem[];
  const int tid = threadIdx.x;
  const int gidx = blockIdx.x;
  const int wave = tid >> 6;
  const int lane = tid & 63;
  const int q = lane >> 4;
  const int l16 = lane & 15;
  unsigned short* Xb = (unsigned short*)smem;
  float* par = (float*)(smem + LDS_PAR);
  float* sqv = (float*)(smem + LDS_SQV);
  float* sm  = (float*)(smem + LDS_SM);
  float* smw = (float*)(smem + LDS_SMW);

  // stage LN/bias params -> LDS (visibility covered by first chunk barrier)
  for (int i = tid; i < 3456; i += 512) {
    float v;
    if (i < 256) v = b_in[i];
    else if (i < 512) v = g_in[i - 256];
    else if (i < 768) v = beta_in[i - 512];
    else if (i < 1536) v = bb[i - 768];
    else if (i < 2304) v = gb[i - 1536];
    else if (i < 3072) v = betab[i - 2304];
    else if (i < 3200) v = b_out[i - 3072];
    else if (i < 3328) v = g_out[i - 3200];
    else v = beta_out[i - 3328];
    par[i] = v;
  }
  // stage H tile (128x64) -> Xb as bf16
  {
    int row = tid >> 2, cb0 = (tid & 3) * 16;
    const float4* hp = reinterpret_cast<const float4*>(H + (size_t)(gidx * 128 + row) * 64 + cb0);
#pragma unroll
    for (int v4 = 0; v4 < 4; ++v4) {
      float4 f = hp[v4];
      int cb = cb0 + v4 * 4;
      Xb[row * XB_STRIDE + cb + 0] = f2bf(f.x);
      Xb[row * XB_STRIDE + cb + 1] = f2bf(f.y);
      Xb[row * XB_STRIDE + cb + 2] = f2bf(f.z);
      Xb[row * XB_STRIDE + cb + 3] = f2bf(f.w);
    }
  }

  layer_gemm<64, 4, 0>(smem, ws, tid, wave, lane, 0, 256, 512, 0);
  layer_gemm<256, 4, 1>(smem, ws + 16384,          tid, wave, lane,  768, 1536, 2304, 1);
  layer_gemm<256, 4, 1>(smem, ws + 16384 + 65536,  tid, wave, lane, 1024, 1792, 2560, 1);
  layer_gemm<256, 4, 1>(smem, ws + 16384 + 131072, tid, wave, lane, 1280, 2048, 2816, 1);
  layer_gemm<256, 2, 2>(smem, ws + 212992,         tid, wave, lane, 3072, 3200, 3328, 1);
  __syncthreads();                       // Z (bf16, Xb cols 0..127) ready for all waves

  // ---- gram G = Z Z^T : wave owns 16 rows x 128 cols
  f32x4 g2[8];
#pragma unroll
  for (int nt = 0; nt < 8; ++nt) g2[nt] = zero4();
#pragma unroll
  for (int ks = 0; ks < 4; ++ks) {
    int kk = ks * 32 + q * 8;
    bf16x8 a = *reinterpret_cast<const bf16x8*>(Xb + (16 * wave + l16) * XB_STRIDE + kk);
#pragma unroll
    for (int nt = 0; nt < 8; ++nt) {
      bf16x8 bfr = *reinterpret_cast<const bf16x8*>(Xb + (16 * nt + l16) * XB_STRIDE + kk);
      g2[nt] = __builtin_amdgcn_mfma_f32_16x16x32_bf16(a, bfr, g2[nt], 0, 0, 0);
    }
  }
  // publish sq_i = G_ii (diag) so that d_ii == sqrt(1e-12) exactly like ref
  if ((l16 >> 2) == q) {
#pragma unroll
    for (int nt = 0; nt < 8; ++nt)
      if (nt == wave) {
#pragma unroll
        for (int r = 0; r < 4; ++r)
          if ((l16 & 3) == r) sqv[16 * wave + l16] = g2[nt][r];
      }
  }
  __syncthreads();
  // ---- distances and s_i = mean_j d_ij
  float sqi[4];
#pragma unroll
  for (int r = 0; r < 4; ++r) sqi[r] = sqv[16 * wave + q * 4 + r];
  float sp[4] = {0.f, 0.f, 0.f, 0.f};
#pragma unroll
  for (int nt = 0; nt < 8; ++nt) {
    float sqj = sqv[16 * nt + l16];
#pragma unroll
    for (int r = 0; r < 4; ++r) {
      float d2 = sqi[r] + sqj - 2.0f * g2[nt][r];
      sp[r] += sqrtf(fmaxf(d2, 0.f) + 1e-12f);
    }
  }
#pragma unroll
  for (int d = 1; d < 16; d <<= 1) {
#pragma unroll
    for (int r = 0; r < 4; ++r) { float t = sp[r]; t += __shfl_xor(t, d); sp[r] = t; }
  }
  if (l16 == 0) {
#pragma unroll
    for (int r = 0; r < 4; ++r) sm[16 * wave + q * 4 + r] = sp[r] * (1.0f / 128.0f);
  }
  __syncthreads();
  // ---- softmax(s/TAU) by wave 0 (1/TAU = 4)
  if (wave == 0) {
    float l0 = sm[lane] * 4.0f;
    float l1 = sm[lane + 64] * 4.0f;
    float mx = fmaxf(l0, l1);
#pragma unroll
    for (int d = 1; d < 64; d <<= 1) mx = fmaxf(mx, __shfl_xor(mx, d));
    float e0 = __expf(l0 - mx), e1 = __expf(l1 - mx);
    float ss = e0 + e1;
#pragma unroll
    for (int d = 1; d < 64; d <<= 1) ss += __shfl_xor(ss, d);
    float inv = 1.0f / ss;
    float w0 = e0 * inv, w1 = e1 * inv;
    smw[lane] = w0;
    smw[lane + 64] = w1;
    out[131072 + gidx * 128 + lane] = w0;
    out[131072 + gidx * 128 + 64 + lane] = w1;
  }
  __syncthreads();
  // ---- v_loc = sum_i w_i * Z[i,:] ; wave covers 16 cols, lanes split rows by q
  {
    int c = 16 * wave + l16;
    float acv = 0.f;
#pragma unroll
    for (int i0 = 0; i0 < 32; ++i0) {
      int i = q * 32 + i0;
      acv += smw[i] * bf2f(Xb[i * XB_STRIDE + c]);
    }
    acv += __shfl_xor(acv, 16);
    acv += __shfl_xor(acv, 32);
    if (q == 0) out[gidx * 128 + c] = acv;
  }
}

// ---------------------------------------------------------------------------
extern "C" void kernel_launch(void* const* d_in, const int* in_sizes, int n_in,
                              void* d_out, int out_size, void* d_ws, size_t ws_size,
                              hipStream_t stream) {
  (void)in_sizes; (void)n_in; (void)out_size; (void)ws_size;
  const float* H        = (const float*)d_in[0];
  // d_in[1] = batch_ptr (uniform 128/graph, unused)
  const float* W_in     = (const float*)d_in[2];
  const float* b_in     = (const float*)d_in[3];
  const float* g_in     = (const float*)d_in[4];
  const float* beta_in  = (const float*)d_in[5];
  const float* Wb       = (const float*)d_in[6];
  const float* bb       = (const float*)d_in[7];
  const float* gb       = (const float*)d_in[8];
  const float* betab    = (const float*)d_in[9];
  const float* W_out    = (const float*)d_in[10];
  const float* b_out    = (const float*)d_in[11];
  const float* g_out    = (const float*)d_in[12];
  const float* beta_out = (const float*)d_in[13];
  float* out = (float*)d_out;
  unsigned short* ws = (unsigned short*)d_ws;

  // re-create bf16 transposed weights every call (ws is re-poisoned each launch)
  prep_weights<<<60, 256, 0, stream>>>(W_in, Wb, W_out, ws);

  hipFuncSetAttribute(reinterpret_cast<const void*>(fused_main),
                      hipFuncAttributeMaxDynamicSharedMemorySize, LDS_TOTAL);
  fused_main<<<1024, 512, LDS_TOTAL, stream>>>(H, ws, b_in, g_in, beta_in,
                                               bb, gb, betab, b_out, g_out, beta_out, out);
}